// Round 3
// baseline (242.051 us; speedup 1.0000x reference)
//
#include <hip/hip_runtime.h>
#include <math.h>

#define NROWS 16384
#define DDIM  4096
#define NEXP  64
#define TOPK  8

#define BM   64
#define BK   16
#define NKT  (DDIM / BK)   // 256 k-tiles
#define LDP  68            // padded leading dim for A/B tiles
#define LDPE 65            // padded leading dim for logits

// Emulates: logits = np.einsum("nd,ed->ne", x, W) [float32, SSE1 sum_of_products:
//   4 mod-4 partial sums, ascending d, separate mul/add rounding, (s0+s1)+(s2+s3)]
// probs = np fp32 softmax (max-subtract, exp, pairwise-8 row sum, IEEE div)
// top_k on fp32 probs, ties -> lower index; gates = tk / (seq-sum(tk) + 1e-9)

__global__ __launch_bounds__(256) void router_np(const float* __restrict__ x,
                                                 const float* __restrict__ W,
                                                 float* __restrict__ out) {
    __shared__ float As[2][BK][LDP];
    __shared__ float Bs[2][BK][LDP];
    __shared__ float lgs[BM][LDPE];

    const int t = threadIdx.x;
    const int block_row = blockIdx.x * BM;

    // staging: 256 threads = 64 rows/experts x 4 k-groups x 4 floats
    const int srow = t >> 2;          // 0..63
    const int sk   = (t & 3) * 4;     // 0,4,8,12

    const float* xa = x + (size_t)(block_row + srow) * DDIM + sk;
    const float* wb = W + (size_t)srow * DDIM + sk;

    // compute: thread (tr, tc) owns rows tr*4.., experts tc*4..
    const int tr = t >> 4;            // 0..15
    const int tc = t & 15;            // 0..15

    float acc[4][4][4];               // [d&3][i][j] partial sums
    #pragma unroll
    for (int p = 0; p < 4; ++p)
        #pragma unroll
        for (int i = 0; i < 4; ++i)
            #pragma unroll
            for (int j = 0; j < 4; ++j) acc[p][i][j] = 0.f;

    // prologue: stage tile 0
    {
        float4 a0 = *(const float4*)(xa);
        float4 b0 = *(const float4*)(wb);
        #pragma unroll
        for (int i = 0; i < 4; ++i) {
            As[0][sk + i][srow] = ((const float*)&a0)[i];
            Bs[0][sk + i][srow] = ((const float*)&b0)[i];
        }
    }

    auto compute_tile = [&](int bsel) {
        #pragma unroll
        for (int k = 0; k < BK; ++k) {       // ascending d within tile
            float a[4], b[4];
            #pragma unroll
            for (int i = 0; i < 4; ++i) a[i] = As[bsel][k][tr * 4 + i];
            #pragma unroll
            for (int j = 0; j < 4; ++j) b[j] = Bs[bsel][k][tc * 4 + j];
            #pragma unroll
            for (int i = 0; i < 4; ++i)
                #pragma unroll
                for (int j = 0; j < 4; ++j)
                    acc[k & 3][i][j] =
                        __fadd_rn(acc[k & 3][i][j], __fmul_rn(a[i], b[j]));
        }
    };

    int buf = 0;
    for (int kt = 0; kt < NKT - 1; ++kt) {
        __syncthreads();
        const float* xn = xa + (size_t)(kt + 1) * BK;
        const float* wn = wb + (size_t)(kt + 1) * BK;
        float4 a0 = *(const float4*)(xn);    // register prefetch of next tile
        float4 b0 = *(const float4*)(wn);

        compute_tile(buf);

        const int nb = buf ^ 1;
        #pragma unroll
        for (int i = 0; i < 4; ++i) {
            As[nb][sk + i][srow] = ((const float*)&a0)[i];
            Bs[nb][sk + i][srow] = ((const float*)&b0)[i];
        }
        buf = nb;
    }

    __syncthreads();
    compute_tile(buf);

    // numpy-einsum SSE reduction tree: (s0+s1)+(s2+s3)
    #pragma unroll
    for (int i = 0; i < 4; ++i)
        #pragma unroll
        for (int j = 0; j < 4; ++j)
            lgs[tr * 4 + i][tc * 4 + j] =
                __fadd_rn(__fadd_rn(acc[0][i][j], acc[1][i][j]),
                          __fadd_rn(acc[2][i][j], acc[3][i][j]));
    __syncthreads();

    float* out_gates = out;
    float* out_idx   = out + (size_t)NROWS * TOPK;
    float* out_probs = out + (size_t)NROWS * TOPK * 2;

    const int wave = t >> 6;           // 0..3
    const int lane = t & 63;           // lane == expert

    for (int rr = 0; rr < BM / 4; ++rr) {
        const int row = wave * (BM / 4) + rr;
        const float l = lgs[row][lane];

        // max over 64 fp32 logits (order-independent)
        float m = l;
        #pragma unroll
        for (int off = 32; off > 0; off >>= 1)
            m = fmaxf(m, __shfl_xor(m, off));

        // e = exp(l - m): fp32 subtract, near-correctly-rounded fp32 exp
        const float e = (float)exp((double)__fsub_rn(l, m));

        // numpy pairwise-8 row sum: r[j] = sum over lanes j, j+8, ..., j+56 (ascending)
        const int j8 = lane & 7;
        float r = __shfl(e, j8);
        #pragma unroll
        for (int s = 1; s < 8; ++s)
            r = __fadd_rn(r, __shfl(e, j8 + s * 8));
        const float r0 = __shfl(r, 0), r1 = __shfl(r, 1), r2 = __shfl(r, 2), r3 = __shfl(r, 3);
        const float r4 = __shfl(r, 4), r5 = __shfl(r, 5), r6 = __shfl(r, 6), r7 = __shfl(r, 7);
        const float S = __fadd_rn(__fadd_rn(__fadd_rn(r0, r1), __fadd_rn(r2, r3)),
                                  __fadd_rn(__fadd_rn(r4, r5), __fadd_rn(r6, r7)));

        const float prob = __fdiv_rn(e, S);

        const size_t grow = (size_t)(block_row + row);
        out_probs[grow * NEXP + lane] = prob;

        // top-8 on fp32 probs; ties -> lower index (lax.top_k / stable argsort)
        float work = prob;
        float myval = 0.f, topsum = 0.f;
        int   myidx = 0;
        for (int it = 0; it < TOPK; ++it) {
            float v = work;
            int   idx = lane;
            #pragma unroll
            for (int off = 32; off > 0; off >>= 1) {
                float ov = __shfl_xor(v, off);
                int   oi = __shfl_xor(idx, off);
                if (ov > v || (ov == v && oi < idx)) { v = ov; idx = oi; }
            }
            const float pw = __shfl(prob, idx);
            topsum = __fadd_rn(topsum, pw);   // rank-order sequential (np.sum, n=8)
            if (lane == idx) work = -1.0f;    // exclude winner (probs >= 0)
            if (lane == it)  { myval = pw; myidx = idx; }
        }
        if (lane < TOPK) {
            out_gates[grow * TOPK + lane] = __fdiv_rn(myval, __fadd_rn(topsum, 1e-9f));
            out_idx[grow * TOPK + lane]   = (float)myidx;
        }
    }
}

extern "C" void kernel_launch(void* const* d_in, const int* in_sizes, int n_in,
                              void* d_out, int out_size, void* d_ws, size_t ws_size,
                              hipStream_t stream) {
    const float* x = (const float*)d_in[0];   // (16384, 4096) fp32
    const float* W = (const float*)d_in[1];   // (64, 4096) fp32
    float* out = (float*)d_out;               // gates(N*8) | indices(N*8) | probs(N*64)

    dim3 grid(NROWS / BM);   // 256 blocks
    dim3 block(256);
    hipLaunchKernelGGL(router_np, grid, block, 0, stream, x, W, out);
}